// Round 8
// baseline (162.089 us; speedup 1.0000x reference)
//
#include <hip/hip_runtime.h>

// apply_cdna_kernels: out[n,b,c,h,w] = sum_{kh,kw} images[b,h+kh-2,w+kw-2,c] * kernels[b,kh,kw,n]
// images: [64,128,128,3] f32   kernels: [64,5,5,10] f32   out: [10,64,3,128,128] f32
//
// R9: kill residual spill. Session evidence: every round's effective BW pins
// at ~3 TB/s; R4/R8's VGPR_Count==128 (exactly the cap) + R4's counter excess
// (FETCH +55MB, WRITE +26MB) decomposes as ~25 spilled VGPRs/thread round-
// tripping scratch. Pressure source = n-pair structure (24 acc + 24 px + ~50
// in-flight weight VGPRs from readfirstlane's forced vector loads).
//  - SINGLE n per inner iteration: 12 acc + 24 px + addr ~ 60 VGPR live.
//    LDS doubling is hidden: 30 ds_read_b128/n (~360 cyc/wave) < 300 FMA
//    (~600 cyc/wave) with 4 waves/SIMD.
//  - weights via plain uniform loads -> compiler s_load path (R0 proved it);
//    no readfirstlane, weights never occupy VGPRs.
//  - keep: plain float4 dwordx4 stores (R8 A/B win vs nt), TH=8 tile,
//    1024 blocks = 4/CU = 16 waves/CU, launch_bounds(256,2) = 128 budget.
// Predict: VGPR ~64-80 (below cap), FETCH ~25MB, WRITE ~128MB, kernel 25-35us.

#define B_  64
#define H_  128
#define W_  128
#define C_  3
#define N_  10
#define KH_ 5
#define KW_ 5
#define TH_ 8                  // tile height (full W width)
#define LDS_ROWS (TH_ + 4)     // 12 rows incl. halo
#define ROW_F ((W_ + 4) * C_)  // 132 px * 3 = 396 floats per row (1584B)
#define ROW_VALID (W_ * C_)    // 384 valid floats per global image row
#define HW_ (H_ * W_)          // 16384

__global__ __launch_bounds__(256, 2) void cdna_apply_kernel(
    const float* __restrict__ images,
    const float* __restrict__ kernels,
    float* __restrict__ out)
{
    __shared__ __align__(16) float s_img[LDS_ROWS * ROW_F];

    const int tid = threadIdx.x;
    const int ht  = blockIdx.x;   // 16
    const int b   = blockIdx.y;   // 64
    const int y0  = ht * TH_;

    // ---- stage image tile (12 rows x 99 float4; zero-padded halo), once ----
    const float* __restrict__ ib = images + (long)b * (H_ * W_ * C_);
    for (int i = tid; i < LDS_ROWS * (ROW_F / 4); i += 256) {
        const int r  = i / (ROW_F / 4);        // LDS row 0..11
        const int q  = i - r * (ROW_F / 4);    // float4 index in row, 0..98
        const int y  = y0 + r - 2;
        float v0 = 0.f, v1 = 0.f, v2 = 0.f, v3 = 0.f;
        if ((unsigned)y < (unsigned)H_) {
            const float* grow = ib + (long)y * ROW_VALID;
            const int f0 = q * 4 - 6;          // offset into 384-float global row (even)
            if (f0 >= 0 && f0 <= ROW_VALID - 4) {
                const float2 a  = *(const float2*)(grow + f0);
                const float2 c2 = *(const float2*)(grow + f0 + 2);
                v0 = a.x; v1 = a.y; v2 = c2.x; v3 = c2.y;
            } else {
                if (f0 + 0 >= 0 && f0 + 0 < ROW_VALID) v0 = grow[f0 + 0];
                if (f0 + 1 >= 0 && f0 + 1 < ROW_VALID) v1 = grow[f0 + 1];
                if (f0 + 2 >= 0 && f0 + 2 < ROW_VALID) v2 = grow[f0 + 2];
                if (f0 + 3 >= 0 && f0 + 3 < ROW_VALID) v3 = grow[f0 + 3];
            }
        }
        *(float4*)(&s_img[r * ROW_F + q * 4]) = make_float4(v0, v1, v2, v3);
    }
    __syncthreads();

    const int tx = tid & 31;      // 4w column group: cols 4tx..4tx+3
    const int ty = tid >> 5;      // 0..7 output row within tile

    const float* __restrict__ kb = kernels + (long)b * (KH_ * KW_ * N_);
    const int h = y0 + ty;
    float* ob0 = out + (long)b * (C_ * HW_) + (long)h * W_ + tx * 4;
    const long nstride = (long)B_ * C_ * HW_;

    #pragma unroll 1
    for (int n = 0; n < N_; ++n) {
        // 25 block-uniform weights: uniform address -> compiler s_load path
        float wt[KH_ * KW_];
        #pragma unroll
        for (int k = 0; k < KH_ * KW_; ++k)
            wt[k] = kb[k * N_ + n];

        float acc[12];                         // [c*4 + w]
        #pragma unroll
        for (int i = 0; i < 12; ++i) acc[i] = 0.f;

        #pragma unroll
        for (int r = 0; r < KH_; ++r) {
            const float4* rp = (const float4*)&s_img[(ty + r) * ROW_F + tx * 12];
            float px[24];                      // pixels x=4tx-2..4tx+5, 3 c each
            #pragma unroll
            for (int j = 0; j < 6; ++j) {      // 6x ds_read_b128, conflict-free
                const float4 t = rp[j];
                px[j * 4 + 0] = t.x; px[j * 4 + 1] = t.y;
                px[j * 4 + 2] = t.z; px[j * 4 + 3] = t.w;
            }
            #pragma unroll
            for (int kw = 0; kw < KW_; ++kw) {
                const float wgt = wt[r * KW_ + kw];
                #pragma unroll
                for (int w = 0; w < 4; ++w)
                    #pragma unroll
                    for (int c = 0; c < C_; ++c)
                        acc[c * 4 + w] = fmaf(px[(kw + w) * 3 + c], wgt, acc[c * 4 + w]);
            }
        }

        // plain dwordx4 stores: 1KB contiguous per wave per (n,c) -> sector-complete
        float* p0 = ob0 + (long)n * nstride;
        #pragma unroll
        for (int c = 0; c < C_; ++c)
            *(float4*)(p0 + (long)c * HW_) =
                make_float4(acc[c*4+0], acc[c*4+1], acc[c*4+2], acc[c*4+3]);
    }
}

extern "C" void kernel_launch(void* const* d_in, const int* in_sizes, int n_in,
                              void* d_out, int out_size, void* d_ws, size_t ws_size,
                              hipStream_t stream) {
    const float* images  = (const float*)d_in[0];
    const float* kernels = (const float*)d_in[1];
    float* out = (float*)d_out;

    dim3 grid(H_ / TH_, B_);   // 16 x 64 = 1024 blocks, 4 per CU
    cdna_apply_kernel<<<grid, 256, 0, stream>>>(images, kernels, out);
}